// Round 13
// baseline (884.705 us; speedup 1.0000x reference)
//
#include <hip/hip_runtime.h>
#include <hip/hip_cooperative_groups.h>
#include <stdint.h>

namespace cg = cooperative_groups;

// Hashgrid encoder, L=16, D=3, C=2, H=16, S=1.
// R13: R12 proved phase-locking kills fabric traffic (FETCH 2.46->0.36GB)
// but dur=662us is L2-hit-latency x MLP bound (16 waves/CU, grid-capped).
// This round: 2 pts/thread -> grid 2048 = 8 blocks/CU (32 waves/CU, 2x MLP);
// dense levels 0-2 moved into the final thread-local pass (no pacing needed,
// tables 2.5MB stay hot); 13 hash phases with 12 pacing syncs only.

constexpr uint32_t OFF[16] = {
    0u, 4920u, 40864u, 315496u, 839784u, 1364072u, 1888360u, 2412648u,
    2936936u, 3461224u, 3985512u, 4509800u, 5034088u, 5558376u, 6082664u, 6606952u
};

#define HASH_ENTRIES 524288u
#define HASH_MASK    (HASH_ENTRIES - 1u)
#define P1 2654435761u
#define P2 805459861u
#define PPT 2   // points per thread (coop path)

typedef float floatx2 __attribute__((ext_vector_type(2)));
typedef float floatx4 __attribute__((ext_vector_type(4)));

// ---- hash level for PPT points: addresses first, then loads, then math ----
template<int L>
__device__ __forceinline__ void hash_phase(
    const float* cx, const float* cy, const float* cz,
    const float2* __restrict__ ext, const float2* __restrict__ own,
    float* __restrict__ ws, int B, int tid, int NT)
{
    static_assert(L >= 3, "hash levels only");
    uint32_t gi[PPT][8];
    float txa[PPT], tya[PPT], tza[PPT];
#pragma unroll
    for (int i = 0; i < PPT; ++i) {
        constexpr float scale = (float)((16u << L) - 1u);   // exact in fp32
        const float px = cx[i] * scale + 0.5f;
        const float py = cy[i] * scale + 0.5f;
        const float pz = cz[i] * scale + 0.5f;
        const float fxf = floorf(px), fyf = floorf(py), fzf = floorf(pz);
        txa[i] = px - fxf; tya[i] = py - fyf; tza[i] = pz - fzf;
        const uint32_t x0 = (uint32_t)(int)fxf;
        const uint32_t y0 = (uint32_t)(int)fyf;
        const uint32_t z0 = (uint32_t)(int)fzf;
        const uint32_t hx0 = x0,       hx1 = x0 + 1u;   // PRIMES[0]==1
        const uint32_t hy0 = y0 * P1,  hy1 = (y0 + 1u) * P1;
        const uint32_t hz0 = z0 * P2,  hz1 = (z0 + 1u) * P2;
#pragma unroll
        for (int c = 0; c < 8; ++c) {
            gi[i][c] = (((c & 1) ? hx1 : hx0) ^
                        ((c & 2) ? hy1 : hy0) ^
                        ((c & 4) ? hz1 : hz0)) & HASH_MASK;
        }
    }

    float2 f[PPT][8];
#pragma unroll
    for (int i = 0; i < PPT; ++i) {
#pragma unroll
        for (int c = 0; c < 8; ++c) {
            if constexpr (L == 3) {
                // level 3 straddles the ext/own boundary at 524288
                const uint32_t gg = gi[i][c] + OFF[3];
                const float2* q = (gg < HASH_ENTRIES)
                                    ? (ext + gg)
                                    : (own + (gg - HASH_ENTRIES));
                f[i][c] = *q;
            } else {
                f[i][c] = own[(OFF[L] - HASH_ENTRIES) + gi[i][c]];
            }
        }
    }

#pragma unroll
    for (int i = 0; i < PPT; ++i) {
        const int p = tid + i * NT;
        if (p >= B) continue;
        float r0 = 0.0f, r1 = 0.0f;
#pragma unroll
        for (int c = 0; c < 8; ++c) {
            const float wi = ((c & 1) ? txa[i] : 1.0f - txa[i])
                           * ((c & 2) ? tya[i] : 1.0f - tya[i])
                           * ((c & 4) ? tza[i] : 1.0f - tza[i]);
            r0 += wi * f[i][c].x;
            r1 += wi * f[i][c].y;
        }
        // compact level-major rows for levels 3..15 (row L-3); full-line nt
        floatx2 v = { r0, r1 };
        __builtin_nontemporal_store(v,
            (floatx2*)(ws + (size_t)(L - 3) * 2 * B + 2 * p));
    }
}

// ---- dense level (0..2): inline compute, tables are 2.5MB cache-hot ----
template<int L>
__device__ __forceinline__ float2 dense_level(
    float x01, float y01, float z01, const float2* __restrict__ ext)
{
    static_assert(L < 3, "dense levels only");
    constexpr float scale = (float)((16u << L) - 1u);
    const float px = x01 * scale + 0.5f;
    const float py = y01 * scale + 0.5f;
    const float pz = z01 * scale + 0.5f;
    const float fxf = floorf(px), fyf = floorf(py), fzf = floorf(pz);
    const float tx = px - fxf, ty = py - fyf, tz = pz - fzf;
    const uint32_t x0 = (uint32_t)(int)fxf;
    const uint32_t y0 = (uint32_t)(int)fyf;
    const uint32_t z0 = (uint32_t)(int)fzf;
    constexpr uint32_t side = (16u << L) + 1u;
    constexpr uint32_t s2 = side * side;
    const uint32_t base = OFF[L] + x0 + y0 * side + z0 * s2;
    float r0 = 0.0f, r1 = 0.0f;
#pragma unroll
    for (int c = 0; c < 8; ++c) {
        const float2 f = ext[base + (uint32_t)(c & 1)
                                  + (uint32_t)((c >> 1) & 1) * side
                                  + (uint32_t)((c >> 2) & 1) * s2];
        const float wi = ((c & 1) ? tx : 1.0f - tx)
                       * ((c & 2) ? ty : 1.0f - ty)
                       * ((c & 4) ? tz : 1.0f - tz);
        r0 += wi * f.x;
        r1 += wi * f.y;
    }
    return make_float2(r0, r1);
}

// ---- cooperative kernel: 2 pts/thread, 8 blocks/CU, phased hash levels ----
__global__ __launch_bounds__(256, 8) void coop_kernel(
    const float* __restrict__ xyz,
    const float2* __restrict__ ext,
    const float2* __restrict__ own,
    float* __restrict__ ws,
    float* __restrict__ out,
    int B)
{
    cg::grid_group grid = cg::this_grid();
    const int NT  = (int)(gridDim.x * 256u);
    const int tid = (int)(blockIdx.x * 256u + threadIdx.x);

    float cx[PPT], cy[PPT], cz[PPT];
#pragma unroll
    for (int i = 0; i < PPT; ++i) {
        const int p = tid + i * NT;
        if (p < B) {
            cx[i] = (__builtin_nontemporal_load(&xyz[3 * p + 0]) + 1.0f) * 0.5f;
            cy[i] = (__builtin_nontemporal_load(&xyz[3 * p + 1]) + 1.0f) * 0.5f;
            cz[i] = (__builtin_nontemporal_load(&xyz[3 * p + 2]) + 1.0f) * 0.5f;
        } else {
            cx[i] = cy[i] = cz[i] = 0.0f;
        }
    }

    // 13 hash phases; pacing syncs BETWEEN phases only (data deps are
    // thread-local, so no sync needed after the last phase).
#define HP(L) hash_phase<L>(cx, cy, cz, ext, own, ws, B, tid, NT)
    HP(3);  grid.sync();
    HP(4);  grid.sync();
    HP(5);  grid.sync();
    HP(6);  grid.sync();
    HP(7);  grid.sync();
    HP(8);  grid.sync();
    HP(9);  grid.sync();
    HP(10); grid.sync();
    HP(11); grid.sync();
    HP(12); grid.sync();
    HP(13); grid.sync();
    HP(14); grid.sync();
    HP(15);
#undef HP

    // final pass: dense levels inline + gather own ws rows -> 128B record
#pragma unroll
    for (int i = 0; i < PPT; ++i) {
        const int p = tid + i * NT;
        if (p >= B) continue;
        float v[32];
        const float2 d0 = dense_level<0>(cx[i], cy[i], cz[i], ext);
        const float2 d1 = dense_level<1>(cx[i], cy[i], cz[i], ext);
        const float2 d2 = dense_level<2>(cx[i], cy[i], cz[i], ext);
        v[0] = d0.x; v[1] = d0.y;
        v[2] = d1.x; v[3] = d1.y;
        v[4] = d2.x; v[5] = d2.y;
#pragma unroll
        for (int l = 3; l < 16; ++l) {
            floatx2 t = __builtin_nontemporal_load(
                (const floatx2*)(ws + (size_t)(l - 3) * 2 * B + 2 * p));
            v[2 * l + 0] = t.x;
            v[2 * l + 1] = t.y;
        }
        floatx4* o4 = (floatx4*)(out + (size_t)p * 32);
#pragma unroll
        for (int k = 0; k < 8; ++k) {
            floatx4 q = { v[4 * k + 0], v[4 * k + 1],
                          v[4 * k + 2], v[4 * k + 3] };
            o4[k] = q;   // plain stores: L2 merges into full lines
        }
    }
}

// ---- fallback: 16 per-level launches, point-major direct stores ----
template<int L>
__global__ __launch_bounds__(256) void phase_kernel(
    const float* __restrict__ xyz,
    const float2* __restrict__ ext,
    const float2* __restrict__ own,
    float* __restrict__ dst,
    int B)
{
    const int b = blockIdx.x * 256 + threadIdx.x;
    if (b >= B) return;
    const float x01 = (__builtin_nontemporal_load(&xyz[3 * b + 0]) + 1.0f) * 0.5f;
    const float y01 = (__builtin_nontemporal_load(&xyz[3 * b + 1]) + 1.0f) * 0.5f;
    const float z01 = (__builtin_nontemporal_load(&xyz[3 * b + 2]) + 1.0f) * 0.5f;
    constexpr float scale = (float)((16u << L) - 1u);
    const float px = x01 * scale + 0.5f;
    const float py = y01 * scale + 0.5f;
    const float pz = z01 * scale + 0.5f;
    const float fxf = floorf(px), fyf = floorf(py), fzf = floorf(pz);
    const float tx = px - fxf, ty = py - fyf, tz = pz - fzf;
    const uint32_t x0 = (uint32_t)(int)fxf;
    const uint32_t y0 = (uint32_t)(int)fyf;
    const uint32_t z0 = (uint32_t)(int)fzf;
    float2 f[8];
    if constexpr (L < 3) {
        constexpr uint32_t side = (16u << L) + 1u;
        constexpr uint32_t s2 = side * side;
        const uint32_t base = OFF[L] + x0 + y0 * side + z0 * s2;
#pragma unroll
        for (int i = 0; i < 8; ++i)
            f[i] = ext[base + (uint32_t)(i & 1)
                           + (uint32_t)((i >> 1) & 1) * side
                           + (uint32_t)((i >> 2) & 1) * s2];
    } else {
        const uint32_t hx0 = x0,       hx1 = x0 + 1u;
        const uint32_t hy0 = y0 * P1,  hy1 = (y0 + 1u) * P1;
        const uint32_t hz0 = z0 * P2,  hz1 = (z0 + 1u) * P2;
#pragma unroll
        for (int i = 0; i < 8; ++i) {
            const uint32_t gi = (((i & 1) ? hx1 : hx0) ^
                                 ((i & 2) ? hy1 : hy0) ^
                                 ((i & 4) ? hz1 : hz0)) & HASH_MASK;
            if constexpr (L == 3) {
                const uint32_t gg = gi + OFF[3];
                const float2* q = (gg < HASH_ENTRIES)
                                    ? (ext + gg)
                                    : (own + (gg - HASH_ENTRIES));
                f[i] = *q;
            } else {
                f[i] = own[(OFF[L] - HASH_ENTRIES) + gi];
            }
        }
    }
    float r0 = 0.0f, r1 = 0.0f;
#pragma unroll
    for (int i = 0; i < 8; ++i) {
        const float wi = ((i & 1) ? tx : 1.0f - tx)
                       * ((i & 2) ? ty : 1.0f - ty)
                       * ((i & 4) ? tz : 1.0f - tz);
        r0 += wi * f[i].x;
        r1 += wi * f[i].y;
    }
    floatx2 v = { r0, r1 };
    *(floatx2*)(dst + (size_t)b * 32 + 2 * L) = v;   // plain 8B store
}

static inline void launch_fallback(const float* xyz, const float2* ext,
                                   const float2* own, float* dst, int B,
                                   int grid, hipStream_t stream) {
    phase_kernel< 0><<<grid, 256, 0, stream>>>(xyz, ext, own, dst, B);
    phase_kernel< 1><<<grid, 256, 0, stream>>>(xyz, ext, own, dst, B);
    phase_kernel< 2><<<grid, 256, 0, stream>>>(xyz, ext, own, dst, B);
    phase_kernel< 3><<<grid, 256, 0, stream>>>(xyz, ext, own, dst, B);
    phase_kernel< 4><<<grid, 256, 0, stream>>>(xyz, ext, own, dst, B);
    phase_kernel< 5><<<grid, 256, 0, stream>>>(xyz, ext, own, dst, B);
    phase_kernel< 6><<<grid, 256, 0, stream>>>(xyz, ext, own, dst, B);
    phase_kernel< 7><<<grid, 256, 0, stream>>>(xyz, ext, own, dst, B);
    phase_kernel< 8><<<grid, 256, 0, stream>>>(xyz, ext, own, dst, B);
    phase_kernel< 9><<<grid, 256, 0, stream>>>(xyz, ext, own, dst, B);
    phase_kernel<10><<<grid, 256, 0, stream>>>(xyz, ext, own, dst, B);
    phase_kernel<11><<<grid, 256, 0, stream>>>(xyz, ext, own, dst, B);
    phase_kernel<12><<<grid, 256, 0, stream>>>(xyz, ext, own, dst, B);
    phase_kernel<13><<<grid, 256, 0, stream>>>(xyz, ext, own, dst, B);
    phase_kernel<14><<<grid, 256, 0, stream>>>(xyz, ext, own, dst, B);
    phase_kernel<15><<<grid, 256, 0, stream>>>(xyz, ext, own, dst, B);
}

extern "C" void kernel_launch(void* const* d_in, const int* in_sizes, int n_in,
                              void* d_out, int out_size, void* d_ws, size_t ws_size,
                              hipStream_t stream) {
    const float*  xyz = (const float*)d_in[0];
    const float2* ext = (const float2*)d_in[1];
    const float2* own = (const float2*)d_in[2];
    float* out = (float*)d_out;
    const int B = in_sizes[0] / 3;
    const size_t need = (size_t)B * 26 * sizeof(float);   // 13 levels x float2

    // Co-residency check for the cooperative path (deterministic per call).
    int dev = 0;
    hipGetDevice(&dev);
    int cus = 0;
    hipDeviceGetAttribute(&cus, hipDeviceAttributeMultiprocessorCount, dev);
    int occ = 0;
    hipOccupancyMaxActiveBlocksPerMultiprocessor(&occ, coop_kernel, 256, 0);
    const int gridNeeded = (B + PPT * 256 - 1) / (PPT * 256);

    if (ws_size >= need && occ > 0 && (long)occ * cus >= gridNeeded) {
        float* ws = (float*)d_ws;
        int Bv = B;
        void* args[6];
        args[0] = (void*)&xyz; args[1] = (void*)&ext; args[2] = (void*)&own;
        args[3] = (void*)&ws;  args[4] = (void*)&out; args[5] = (void*)&Bv;
        hipLaunchCooperativeKernel((const void*)coop_kernel,
                                   dim3(gridNeeded), dim3(256), args, 0, stream);
    } else {
        const int grid = (B + 255) / 256;
        launch_fallback(xyz, ext, own, out, B, grid, stream);
    }
}

// Round 15
// 815.210 us; speedup vs baseline: 1.0852x; 1.0852x over previous
//
#include <hip/hip_runtime.h>
#include <hip/hip_cooperative_groups.h>
#include <stdint.h>

namespace cg = cooperative_groups;

// Hashgrid encoder, L=16, D=3, C=2, H=16, S=1.
// R14 = R12 (best: 662us) + ONE change: hash-table gathers use agent-scope
// relaxed loads (L1-bypass). Rationale: R13 doubled occupancy (16->32
// waves/CU) with NO gather speedup -> limiter is the per-CU outstanding-
// miss pool (L1 MSHR ~2.8cy/line), not wave parallelism. Agent-scope loads
// skip L1 (useless anyway: 4MB table vs 32KB L1) and use the deeper
// L2-side queues. Dense levels keep plain loads (real L1 reuse).
// Also removed the final (dead) grid.sync before the thread-local transpose.

constexpr uint32_t OFF[16] = {
    0u, 4920u, 40864u, 315496u, 839784u, 1364072u, 1888360u, 2412648u,
    2936936u, 3461224u, 3985512u, 4509800u, 5034088u, 5558376u, 6082664u, 6606952u
};

#define HASH_ENTRIES 524288u
#define HASH_MASK    (HASH_ENTRIES - 1u)
#define P1 2654435761u
#define P2 805459861u

typedef float floatx2 __attribute__((ext_vector_type(2)));
typedef float floatx4 __attribute__((ext_vector_type(4)));

// agent-scope relaxed 8B load: bypasses (non-coherent) L1, full rate.
__device__ __forceinline__ float2 tbl_load(const float2* p) {
    unsigned long long u = __hip_atomic_load(
        (const unsigned long long*)p, __ATOMIC_RELAXED, __HIP_MEMORY_SCOPE_AGENT);
    union { unsigned long long u; float2 f; } c;
    c.u = u;
    return c.f;
}

// ---- per-level gather+interp, level is compile-time ----
template<int L>
__device__ __forceinline__ void do_level(
    float x01, float y01, float z01,
    const float2* __restrict__ ext, const float2* __restrict__ own,
    float* __restrict__ ws, int B, int p)
{
    constexpr float scale = (float)((16u << L) - 1u);   // exact in fp32
    const float px = x01 * scale + 0.5f;
    const float py = y01 * scale + 0.5f;
    const float pz = z01 * scale + 0.5f;
    const float fxf = floorf(px), fyf = floorf(py), fzf = floorf(pz);
    const float tx = px - fxf, ty = py - fyf, tz = pz - fzf;
    const uint32_t x0 = (uint32_t)(int)fxf;
    const uint32_t y0 = (uint32_t)(int)fyf;
    const uint32_t z0 = (uint32_t)(int)fzf;

    float2 f[8];
    if constexpr (L < 3) {
        constexpr uint32_t side = (16u << L) + 1u;
        constexpr uint32_t s2 = side * side;
        const uint32_t base = OFF[L] + x0 + y0 * side + z0 * s2;
#pragma unroll
        for (int i = 0; i < 8; ++i) {
            f[i] = ext[base + (uint32_t)(i & 1)
                           + (uint32_t)((i >> 1) & 1) * side
                           + (uint32_t)((i >> 2) & 1) * s2];
        }
    } else {
        const uint32_t hx0 = x0,       hx1 = x0 + 1u;   // PRIMES[0]==1
        const uint32_t hy0 = y0 * P1,  hy1 = (y0 + 1u) * P1;
        const uint32_t hz0 = z0 * P2,  hz1 = (z0 + 1u) * P2;
#pragma unroll
        for (int i = 0; i < 8; ++i) {
            const uint32_t gi = (((i & 1) ? hx1 : hx0) ^
                                 ((i & 2) ? hy1 : hy0) ^
                                 ((i & 4) ? hz1 : hz0)) & HASH_MASK;
            if constexpr (L == 3) {
                const uint32_t gg = gi + OFF[3];   // straddles ext/own split
                const float2* q = (gg < HASH_ENTRIES)
                                    ? (ext + gg)
                                    : (own + (gg - HASH_ENTRIES));
                f[i] = tbl_load(q);
            } else {
                f[i] = tbl_load(own + (OFF[L] - HASH_ENTRIES) + gi);
            }
        }
    }

    float r0 = 0.0f, r1 = 0.0f;
#pragma unroll
    for (int i = 0; i < 8; ++i) {
        const float wi = ((i & 1) ? tx : 1.0f - tx)
                       * ((i & 2) ? ty : 1.0f - ty)
                       * ((i & 4) ? tz : 1.0f - tz);
        r0 += wi * f[i].x;
        r1 += wi * f[i].y;
    }
    // level-major, full-line coalesced; nt keeps the hash table in L2
    floatx2 v = { r0, r1 };
    __builtin_nontemporal_store(v, (floatx2*)(ws + (size_t)L * 2 * B + 2 * p));
}

// ---- cooperative all-levels kernel: 4 points/thread, sync between levels ----
__global__ __launch_bounds__(256, 4) void coop_kernel(
    const float* __restrict__ xyz,
    const float2* __restrict__ ext,
    const float2* __restrict__ own,
    float* __restrict__ ws,
    float* __restrict__ out,
    int B)
{
    cg::grid_group grid = cg::this_grid();
    const int NT  = (int)(gridDim.x * 256u);
    const int tid = (int)(blockIdx.x * 256u + threadIdx.x);

    // cache coords for the thread's (up to) 4 points in registers
    float cx[4], cy[4], cz[4];
#pragma unroll
    for (int i = 0; i < 4; ++i) {
        const int p = tid + i * NT;
        if (p < B) {
            cx[i] = (__builtin_nontemporal_load(&xyz[3 * p + 0]) + 1.0f) * 0.5f;
            cy[i] = (__builtin_nontemporal_load(&xyz[3 * p + 1]) + 1.0f) * 0.5f;
            cz[i] = (__builtin_nontemporal_load(&xyz[3 * p + 2]) + 1.0f) * 0.5f;
        } else {
            cx[i] = cy[i] = cz[i] = 0.0f;
        }
    }

    // 16 phase-locked levels; pacing sync BETWEEN phases (last one removed:
    // the transpose below is thread-local, no cross-thread dependency).
#define LEVEL_STEP(L, SYNC)                                                  \
    {                                                                        \
        _Pragma("unroll")                                                    \
        for (int i = 0; i < 4; ++i) {                                        \
            const int p = tid + i * NT;                                      \
            if (p < B) do_level<L>(cx[i], cy[i], cz[i], ext, own, ws, B, p); \
        }                                                                    \
        if (SYNC) grid.sync();                                               \
    }

    LEVEL_STEP(0, 1)  LEVEL_STEP(1, 1)  LEVEL_STEP(2, 1)  LEVEL_STEP(3, 1)
    LEVEL_STEP(4, 1)  LEVEL_STEP(5, 1)  LEVEL_STEP(6, 1)  LEVEL_STEP(7, 1)
    LEVEL_STEP(8, 1)  LEVEL_STEP(9, 1)  LEVEL_STEP(10, 1) LEVEL_STEP(11, 1)
    LEVEL_STEP(12, 1) LEVEL_STEP(13, 1) LEVEL_STEP(14, 1) LEVEL_STEP(15, 0)
#undef LEVEL_STEP

    // in-kernel transpose: each thread gathers its OWN points' level-major
    // rows -> one contiguous 128B record. PLAIN loads/stores (R6/R9
    // evidence: plain stores merge in L2; nt 16B stores amplify 3x).
#pragma unroll
    for (int i = 0; i < 4; ++i) {
        const int p = tid + i * NT;
        if (p >= B) continue;
        float v[32];
#pragma unroll
        for (int l = 0; l < 16; ++l) {
            floatx2 t = *(const floatx2*)(ws + (size_t)l * 2 * B + 2 * p);
            v[2 * l + 0] = t.x;
            v[2 * l + 1] = t.y;
        }
        floatx4* o4 = (floatx4*)(out + (size_t)p * 32);
#pragma unroll
        for (int k = 0; k < 8; ++k) {
            floatx4 q = { v[4 * k + 0], v[4 * k + 1],
                          v[4 * k + 2], v[4 * k + 3] };
            o4[k] = q;
        }
    }
}

// ---- fallback path: 16 per-level launches + separate transpose ----
template<int L, bool DIRECT>
__global__ __launch_bounds__(256) void phase_kernel(
    const float* __restrict__ xyz,
    const float2* __restrict__ ext,
    const float2* __restrict__ own,
    float* __restrict__ dst,
    int B)
{
    const int b = blockIdx.x * 256 + threadIdx.x;
    if (b >= B) return;
    const float x01 = (__builtin_nontemporal_load(&xyz[3 * b + 0]) + 1.0f) * 0.5f;
    const float y01 = (__builtin_nontemporal_load(&xyz[3 * b + 1]) + 1.0f) * 0.5f;
    const float z01 = (__builtin_nontemporal_load(&xyz[3 * b + 2]) + 1.0f) * 0.5f;
    if constexpr (DIRECT) {
        constexpr float scale = (float)((16u << L) - 1u);
        const float px = x01 * scale + 0.5f;
        const float py = y01 * scale + 0.5f;
        const float pz = z01 * scale + 0.5f;
        const float fxf = floorf(px), fyf = floorf(py), fzf = floorf(pz);
        const float tx = px - fxf, ty = py - fyf, tz = pz - fzf;
        const uint32_t x0 = (uint32_t)(int)fxf;
        const uint32_t y0 = (uint32_t)(int)fyf;
        const uint32_t z0 = (uint32_t)(int)fzf;
        float2 f[8];
        if constexpr (L < 3) {
            constexpr uint32_t side = (16u << L) + 1u;
            constexpr uint32_t s2 = side * side;
            const uint32_t base = OFF[L] + x0 + y0 * side + z0 * s2;
#pragma unroll
            for (int i = 0; i < 8; ++i)
                f[i] = ext[base + (uint32_t)(i & 1)
                               + (uint32_t)((i >> 1) & 1) * side
                               + (uint32_t)((i >> 2) & 1) * s2];
        } else {
            const uint32_t hx0 = x0,       hx1 = x0 + 1u;
            const uint32_t hy0 = y0 * P1,  hy1 = (y0 + 1u) * P1;
            const uint32_t hz0 = z0 * P2,  hz1 = (z0 + 1u) * P2;
#pragma unroll
            for (int i = 0; i < 8; ++i) {
                const uint32_t gi = (((i & 1) ? hx1 : hx0) ^
                                     ((i & 2) ? hy1 : hy0) ^
                                     ((i & 4) ? hz1 : hz0)) & HASH_MASK;
                if constexpr (L == 3) {
                    const uint32_t gg = gi + OFF[3];
                    const float2* q = (gg < HASH_ENTRIES)
                                        ? (ext + gg)
                                        : (own + (gg - HASH_ENTRIES));
                    f[i] = tbl_load(q);
                } else {
                    f[i] = tbl_load(own + (OFF[L] - HASH_ENTRIES) + gi);
                }
            }
        }
        float r0 = 0.0f, r1 = 0.0f;
#pragma unroll
        for (int i = 0; i < 8; ++i) {
            const float wi = ((i & 1) ? tx : 1.0f - tx)
                           * ((i & 2) ? ty : 1.0f - ty)
                           * ((i & 4) ? tz : 1.0f - tz);
            r0 += wi * f[i].x;
            r1 += wi * f[i].y;
        }
        floatx2 v = { r0, r1 };
        *(floatx2*)(dst + (size_t)b * 32 + 2 * L) = v;
    } else {
        do_level<L>(x01, y01, z01, ext, own, dst, B, b);
    }
}

__global__ __launch_bounds__(256) void transpose_kernel(
    const float* __restrict__ ws, float* __restrict__ out, int B)
{
    const int b = blockIdx.x * 256 + threadIdx.x;
    if (b >= B) return;
    float v[32];
#pragma unroll
    for (int l = 0; l < 16; ++l) {
        floatx2 t = *(const floatx2*)(ws + (size_t)l * 2 * B + 2 * b);
        v[2 * l + 0] = t.x;
        v[2 * l + 1] = t.y;
    }
    floatx4* o4 = (floatx4*)(out + (size_t)b * 32);
#pragma unroll
    for (int k = 0; k < 8; ++k) {
        floatx4 q = { v[4 * k + 0], v[4 * k + 1], v[4 * k + 2], v[4 * k + 3] };
        o4[k] = q;   // plain stores: L2 merges into full lines
    }
}

template<bool DIRECT>
static inline void launch_phases(const float* xyz, const float2* ext,
                                 const float2* own, float* dst, int B,
                                 int grid, hipStream_t stream) {
    phase_kernel< 0, DIRECT><<<grid, 256, 0, stream>>>(xyz, ext, own, dst, B);
    phase_kernel< 1, DIRECT><<<grid, 256, 0, stream>>>(xyz, ext, own, dst, B);
    phase_kernel< 2, DIRECT><<<grid, 256, 0, stream>>>(xyz, ext, own, dst, B);
    phase_kernel< 3, DIRECT><<<grid, 256, 0, stream>>>(xyz, ext, own, dst, B);
    phase_kernel< 4, DIRECT><<<grid, 256, 0, stream>>>(xyz, ext, own, dst, B);
    phase_kernel< 5, DIRECT><<<grid, 256, 0, stream>>>(xyz, ext, own, dst, B);
    phase_kernel< 6, DIRECT><<<grid, 256, 0, stream>>>(xyz, ext, own, dst, B);
    phase_kernel< 7, DIRECT><<<grid, 256, 0, stream>>>(xyz, ext, own, dst, B);
    phase_kernel< 8, DIRECT><<<grid, 256, 0, stream>>>(xyz, ext, own, dst, B);
    phase_kernel< 9, DIRECT><<<grid, 256, 0, stream>>>(xyz, ext, own, dst, B);
    phase_kernel<10, DIRECT><<<grid, 256, 0, stream>>>(xyz, ext, own, dst, B);
    phase_kernel<11, DIRECT><<<grid, 256, 0, stream>>>(xyz, ext, own, dst, B);
    phase_kernel<12, DIRECT><<<grid, 256, 0, stream>>>(xyz, ext, own, dst, B);
    phase_kernel<13, DIRECT><<<grid, 256, 0, stream>>>(xyz, ext, own, dst, B);
    phase_kernel<14, DIRECT><<<grid, 256, 0, stream>>>(xyz, ext, own, dst, B);
    phase_kernel<15, DIRECT><<<grid, 256, 0, stream>>>(xyz, ext, own, dst, B);
}

extern "C" void kernel_launch(void* const* d_in, const int* in_sizes, int n_in,
                              void* d_out, int out_size, void* d_ws, size_t ws_size,
                              hipStream_t stream) {
    const float*  xyz = (const float*)d_in[0];
    const float2* ext = (const float2*)d_in[1];
    const float2* own = (const float2*)d_in[2];
    float* out = (float*)d_out;
    const int B = in_sizes[0] / 3;
    const int grid = (B + 255) / 256;
    const size_t need = (size_t)B * 32 * sizeof(float);

    // Co-residency check for the cooperative path (deterministic per call).
    int dev = 0;
    hipGetDevice(&dev);
    int cus = 0;
    hipDeviceGetAttribute(&cus, hipDeviceAttributeMultiprocessorCount, dev);
    int occ = 0;
    hipOccupancyMaxActiveBlocksPerMultiprocessor(&occ, coop_kernel, 256, 0);
    const int gridNeeded = (B + 4 * 256 - 1) / (4 * 256);   // 4 points/thread

    if (ws_size >= need && occ > 0 && (long)occ * cus >= gridNeeded) {
        float* ws = (float*)d_ws;
        int Bv = B;
        void* args[6];
        args[0] = (void*)&xyz; args[1] = (void*)&ext; args[2] = (void*)&own;
        args[3] = (void*)&ws;  args[4] = (void*)&out; args[5] = (void*)&Bv;
        hipLaunchCooperativeKernel((const void*)coop_kernel,
                                   dim3(gridNeeded), dim3(256), args, 0, stream);
    } else if (ws_size >= need) {
        float* ws = (float*)d_ws;
        launch_phases<false>(xyz, ext, own, ws, B, grid, stream);
        transpose_kernel<<<grid, 256, 0, stream>>>(ws, out, B);
    } else {
        launch_phases<true>(xyz, ext, own, out, B, grid, stream);
    }
}